// Round 4
// baseline (163.140 us; speedup 1.0000x reference)
//
#include <hip/hip_runtime.h>
#include <math.h>

#define Udim 13
#define Vdim 13
#define HW 20480               // 128*160
#define UV 169
#define TRUNC 4
#define NPIX (8 * HW)          // 163840
#define PIX_PER_BLK 64
#define LDS_STRIDE 65          // 64 pixels + 1 pad float

typedef const __attribute__((address_space(1))) void glb_void;
typedef __attribute__((address_space(3))) void lds_void;

// Stage all 169 planes x 64 pixels into LDS via async global_load_lds
// (no VGPR results -> compiler can't chunk the loads; ~43 outstanding per
// wave, ~500 per CU). Compute: 4 threads/pixel (lane = 16 pixels x 4
// plane-groups), shuffle-combine argmax and masked-exp sums.
__global__ __launch_bounds__(256) void flow_regression_kernel(
    const float* __restrict__ x, float* __restrict__ out) {
    __shared__ float lds[UV * LDS_STRIDE];   // 43,940 B -> 3 blocks/CU

    int t    = threadIdx.x;
    int wave = t >> 6;
    int lane = t & 63;
    int pix0 = blockIdx.x * PIX_PER_BLK;     // HW%64==0 -> b uniform per block
    int b    = pix0 / HW;
    int hw0  = pix0 - b * HW;

    const float* gbase = x + (size_t)b * UV * HW + hw0;

    // ---- Async stage: wave w loads planes w, w+4, ... (43 fire-and-forget
    // instrs, 256B contiguous global each, LDS dest wave-uniform + lane*4) ----
    for (int pl = wave; pl < UV; pl += 4) {
        const float* gp = gbase + (size_t)pl * HW + lane;
        float* lp = &lds[pl * LDS_STRIDE];
        __builtin_amdgcn_global_load_lds((glb_void*)gp, (lds_void*)lp, 4, 0, 0);
    }
    __builtin_amdgcn_s_waitcnt(0);   // drain vmcnt (my wave's async stores to LDS)
    __syncthreads();

    int q    = lane >> 4;                    // plane-group 0..3
    int pcol = (wave << 4) | (lane & 15);    // local pixel 0..63
    int base_pl = q * 43;                    // groups: 43,43,43,40 planes
    int npl     = (q == 3) ? 40 : 43;

    // ---- Pass 1: argmax (strict > => first index on ties) ----
    float m = -INFINITY;
    int mi = base_pl;
    #pragma unroll
    for (int i = 0; i < 43; ++i) {
        if (i < npl) {
            float v = lds[(base_pl + i) * LDS_STRIDE + pcol];
            if (v > m) { m = v; mi = base_pl + i; }
        }
    }
    // combine over the 4 groups (lanes l, l^16, l^32, l^48 share a pixel)
    {
        float om = __shfl_xor(m, 16); int oi = __shfl_xor(mi, 16);
        if (om > m || (om == m && oi < mi)) { m = om; mi = oi; }
        om = __shfl_xor(m, 32); oi = __shfl_xor(mi, 32);
        if (om > m || (om == m && oi < mi)) { m = om; mi = oi; }
    }
    int ui = mi / Vdim;
    int vi = mi - ui * Vdim;

    // ---- Pass 2: masked exp sums from LDS ----
    float s = 0.f, su = 0.f, sv = 0.f;
    int u = base_pl / Vdim;
    int v = base_pl - u * Vdim;              // (0,0) (3,4) (6,8) (9,12)
    #pragma unroll
    for (int i = 0; i < 43; ++i) {
        if (i < npl) {
            float val = lds[(base_pl + i) * LDS_STRIDE + pcol];
            bool in = (u - ui <= TRUNC) && (ui - u <= TRUNC) &&
                      (v - vi <= TRUNC) && (vi - v <= TRUNC);
            float e = in ? __expf(val - m) : 0.f;
            s  += e;
            su += e * (float)(u - 6);
            sv += e * (float)(v - 6);
        }
        if (++v == Vdim) { v = 0; ++u; }
    }
    s  += __shfl_xor(s, 16);  su += __shfl_xor(su, 16);  sv += __shfl_xor(sv, 16);
    s  += __shfl_xor(s, 32);  su += __shfl_xor(su, 32);  sv += __shfl_xor(sv, 32);

    if (q == 0) {
        float inv = 1.0f / s;
        float* ob = out + (size_t)b * 2 * HW + (hw0 + pcol);
        ob[0]  = su * inv;   // flowU
        ob[HW] = sv * inv;   // flowV
    }
}

extern "C" void kernel_launch(void* const* d_in, const int* in_sizes, int n_in,
                              void* d_out, int out_size, void* d_ws, size_t ws_size,
                              hipStream_t stream) {
    const float* x = (const float*)d_in[0];
    float* out = (float*)d_out;
    flow_regression_kernel<<<NPIX / PIX_PER_BLK, 256, 0, stream>>>(x, out);
}